// Round 10
// baseline (439.499 us; speedup 1.0000x reference)
//
#include <hip/hip_runtime.h>
#include <hip/hip_bf16.h>
#include <stdint.h>

#define L_ 2048
#define S_ 2048
#define D_ 64

typedef float f32x4 __attribute__((ext_vector_type(4)));
typedef __bf16 bf16x8 __attribute__((ext_vector_type(8)));

__device__ __forceinline__ unsigned short f2b(float x) {
    return __builtin_bit_cast(unsigned short, (__bf16)x);
}
__device__ __forceinline__ float h2f(unsigned short u) {
    return (float)__builtin_bit_cast(_Float16, u);
}

// ============ prep 1: K fp32 -> K2 bf16 in per-(ci,lane) frag order ========
// K2 flat 16B units: t = ((((bh*8+it)*8+w)*2+nt)*2+ks)*64 + lan
// value e of unit = K[bh][s = it*256+w*32+nt*16+li][d = ks*32+g*8+e]
// main kernel: ci = it*8+w s-chunk of 32; within chunk unit (nt*2+ks)*64+lan
__global__ void convk2_kernel(const float* __restrict__ k, unsigned short* __restrict__ k2) {
    const int t = blockIdx.x * 256 + threadIdx.x;       // 1,048,576 total
    const int lan = t & 63, ks = (t >> 6) & 1, nt = (t >> 7) & 1;
    const int w = (t >> 8) & 7, it = (t >> 11) & 7, bh = t >> 14;
    const int li = lan & 15, g = lan >> 4;
    const int s  = it * 256 + w * 32 + nt * 16 + li;
    const int d0 = ks * 32 + g * 8;
    const float* src = k + ((size_t)bh * S_ + s) * D_ + d0;
    float4 a = *(const float4*)src;
    float4 b = *(const float4*)(src + 4);
    uint4 o;
    o.x = (unsigned)f2b(a.x) | ((unsigned)f2b(a.y) << 16);
    o.y = (unsigned)f2b(a.z) | ((unsigned)f2b(a.w) << 16);
    o.z = (unsigned)f2b(b.x) | ((unsigned)f2b(b.y) << 16);
    o.w = (unsigned)f2b(b.z) | ((unsigned)f2b(b.w) << 16);
    *(uint4*)(k2 + (size_t)t * 8) = o;
}

// ============ prep 2: V fp32 -> V2 bf16 frag order =========================
// V2 16B units: t = ((((bh*8+it)*8+w)*4+dt)*64) + lan
// value e = V[bh][s = it*256+w*32+g*8+e][d = dt*16+li]
// main kernel: within ci chunk, unit dt*64+lan
__global__ void convv2_kernel(const float* __restrict__ v, unsigned short* __restrict__ v2) {
    const int t = blockIdx.x * 256 + threadIdx.x;       // 1,048,576 total
    const int lan = t & 63, dt = (t >> 6) & 3;
    const int w = (t >> 8) & 7, it = (t >> 11) & 7, bh = t >> 14;
    const int li = lan & 15, g = lan >> 4;
    const int s0 = it * 256 + w * 32 + g * 8;
    const int d  = dt * 16 + li;
    unsigned short o[8];
    #pragma unroll
    for (int e = 0; e < 8; ++e)
        o[e] = f2b(v[((size_t)bh * S_ + s0 + e) * D_ + d]);
    uint4 u;
    u.x = (unsigned)o[0] | ((unsigned)o[1] << 16);
    u.y = (unsigned)o[2] | ((unsigned)o[3] << 16);
    u.z = (unsigned)o[4] | ((unsigned)o[5] << 16);
    u.w = (unsigned)o[6] | ((unsigned)o[7] << 16);
    *(uint4*)(v2 + (size_t)t * 8) = u;
}

// ============ prep 3: bias+mask -> mb2 f16 in per-(lt16,ci,lane) order =====
// mb2 16B units: t = (((b*128+lt)*8+it)*512) + tid512; per 16-row slice lt
// contiguous in ci: slice_base + ci*512 shorts.
// val[nt*4+j] = masked ? -60000 : bias[b][lt*16+g*4+j][it*256+w*32+nt*16+li]
__global__ void fusemb2_kernel(const float* __restrict__ bias, const void* __restrict__ maskp,
                               unsigned short* __restrict__ mb2) {
    const unsigned* mw = (const unsigned*)maskp;
    int is4 = 1;
    for (int i = 0; i < 64; ++i) {
        unsigned wv = mw[i];
        if (!(wv == 0u || wv == 1u || wv == 0x3F800000u)) { is4 = 0; break; }
    }
    const int t = blockIdx.x * 256 + threadIdx.x;       // 2,097,152 total
    const int tid = t & 511, it = (t >> 9) & 7, lt = (t >> 12) & 127, b = t >> 19;
    const int w = tid >> 6, lan = tid & 63, g = lan >> 4, li = lan & 15;
    const unsigned short NEG = __builtin_bit_cast(unsigned short, (_Float16)(-60000.0f));
    const int* maski = (const int*)maskp;
    const unsigned char* maskb = (const unsigned char*)maskp;
    unsigned short o[8];
    #pragma unroll
    for (int nt = 0; nt < 2; ++nt)
      #pragma unroll
      for (int j = 0; j < 4; ++j) {
          size_t idx = ((size_t)b * L_ + lt * 16 + g * 4 + j) * S_
                     + it * 256 + w * 32 + nt * 16 + li;
          int m = is4 ? (maski[idx] != 0) : (maskb[idx] != 0);
          o[nt * 4 + j] = m ? NEG
                            : __builtin_bit_cast(unsigned short, (_Float16)bias[idx]);
      }
    uint4 u;
    u.x = (unsigned)o[0] | ((unsigned)o[1] << 16);
    u.y = (unsigned)o[2] | ((unsigned)o[3] << 16);
    u.z = (unsigned)o[4] | ((unsigned)o[5] << 16);
    u.w = (unsigned)o[6] | ((unsigned)o[7] << 16);
    *(uint4*)(mb2 + (size_t)t * 8) = u;
}

// ============ main fused attention: flash 2-pass, 16 waves/CU ==============
// Round-5 structure (2048 blocks x 4 autonomous waves, 16 rows/wave, 2-pass
// defer-max, global->register streams, zero barriers) with the residency
// fixed properly: __launch_bounds__(256,4) = 128-VGPR budget that the
// 16-row live-set (~110: kf16+vf16+oacc16+qf8+sums8+mbv8+addr16) actually
// clears without spills (round-5's (256,5) forced a 102-reg clamp -> likely
// spills; round-9's rg=2 at 128 could never fit -> silent failure).
// Result: 4 blocks/CU, 4096 resident waves, grid 8192 waves -> EXACTLY two
// uniform generations (zero packing stretch) and 2x round-8's TLP to cover
// the load->MFMA->exp chains and the 181us attn write-wall. Cost vs round 8:
// K/mb2 L2 reads x2 (+~93us of 34.5TB/s fabric, overlappable) -- traded for
// doubled latency hiding on a ~150us stall gap.
__launch_bounds__(256, 4)
__global__ void attn_main_kernel(const float* __restrict__ q,
                                 const unsigned short* __restrict__ mb2,
                                 const unsigned short* __restrict__ k2,
                                 const unsigned short* __restrict__ v2,
                                 float* __restrict__ outp,
                                 float* __restrict__ attnp)
{
    __shared__ __align__(16) char lds[5120];     // 4 waves x 1280 B P-bounce
    const int tid = threadIdx.x;
    const int w = tid >> 6, lan = tid & 63, g = lan >> 4, li = lan & 15;
    char* pbuf = lds + w * 1280;                 // per-wave P tile [16][80B]

    // XCD chunking (bijective, 2048 % 8 == 0): XCD x gets 256 consecutive c.
    // h-inner: 16 consecutive blocks = same (b,lt64), h=0..15 -> mb2 slice
    // reuse window is a ~16-block neighborhood (L2); same-h blocks share K/V.
    const int c     = ((blockIdx.x & 7) << 8) | (blockIdx.x >> 3);
    const int x     = c >> 8;
    const int cl    = c & 255;
    const int combo = (x << 4) | (cl >> 4);      // [0,128) = 4 b x 32 lt64
    const int h     = cl & 15;
    const int b     = combo >> 5;
    const int lt64  = combo & 31;
    const int bh    = (b << 4) | h;
    const int ltp   = lt64 * 4 + w;              // this wave's 16-row slice
    const int l0w   = ltp * 16;

    const unsigned short* mbbase = mb2 + (size_t)(b * 128 + ltp) * 32768 + (size_t)lan * 8;
    const unsigned short* kbase  = k2 + (size_t)bh * 131072 + (size_t)lan * 8;
    const unsigned short* vbase  = v2 + (size_t)bh * 131072 + (size_t)lan * 8;
    const f32x4 vzero = {0.f, 0.f, 0.f, 0.f};

    // ---- Q fragments (regs, both passes) ----
    bf16x8 qf[2];
    #pragma unroll
    for (int ks = 0; ks < 2; ++ks) {
        const float* qp = q + ((size_t)bh * L_ + (l0w + li)) * D_ + ks * 32 + g * 8;
        float4 xv = *(const float4*)qp;
        float4 yv = *(const float4*)(qp + 4);
        bf16x8 f;
        f[0]=(__bf16)xv.x; f[1]=(__bf16)xv.y; f[2]=(__bf16)xv.z; f[3]=(__bf16)xv.w;
        f[4]=(__bf16)yv.x; f[5]=(__bf16)yv.y; f[6]=(__bf16)yv.z; f[7]=(__bf16)yv.w;
        qf[ks] = f;
    }

    // ================= pass 1: row sums (wave-local) =================
    float vs[4] = {0.f, 0.f, 0.f, 0.f};
    #pragma unroll 1
    for (int ci = 0; ci < 64; ++ci) {
        const unsigned short* kit = kbase + ci * 2048;
        uint4 f00 = *(const uint4*)(kit);            // nt0 ks0
        uint4 f01 = *(const uint4*)(kit + 512);      // nt0 ks1
        uint4 f10 = *(const uint4*)(kit + 1024);     // nt1 ks0
        uint4 f11 = *(const uint4*)(kit + 1536);     // nt1 ks1
        uint4 mp  = *(const uint4*)(mbbase + ci * 512);
        f32x4 a0 = vzero, a1 = vzero;
        a0 = __builtin_amdgcn_mfma_f32_16x16x32_bf16(
            qf[0], __builtin_bit_cast(bf16x8, f00), a0, 0, 0, 0);
        a0 = __builtin_amdgcn_mfma_f32_16x16x32_bf16(
            qf[1], __builtin_bit_cast(bf16x8, f01), a0, 0, 0, 0);
        a1 = __builtin_amdgcn_mfma_f32_16x16x32_bf16(
            qf[0], __builtin_bit_cast(bf16x8, f10), a1, 0, 0, 0);
        a1 = __builtin_amdgcn_mfma_f32_16x16x32_bf16(
            qf[1], __builtin_bit_cast(bf16x8, f11), a1, 0, 0, 0);
        float mbv[2][4];
        mbv[0][0] = h2f((unsigned short)(mp.x & 0xffff));
        mbv[0][1] = h2f((unsigned short)(mp.x >> 16));
        mbv[0][2] = h2f((unsigned short)(mp.y & 0xffff));
        mbv[0][3] = h2f((unsigned short)(mp.y >> 16));
        mbv[1][0] = h2f((unsigned short)(mp.z & 0xffff));
        mbv[1][1] = h2f((unsigned short)(mp.z >> 16));
        mbv[1][2] = h2f((unsigned short)(mp.w & 0xffff));
        mbv[1][3] = h2f((unsigned short)(mp.w >> 16));
        #pragma unroll
        for (int j = 0; j < 4; ++j) {
            float e0 = __expf(fmaf(a0[j], 0.125f, mbv[0][j]));
            float e1 = __expf(fmaf(a1[j], 0.125f, mbv[1][j]));
            vs[j] += e0 + e1;
        }
    }
    // wave-local reduce over the 16 li lanes (rows stay per-g) -> 1/sum
    float rinv[4];
    #pragma unroll
    for (int j = 0; j < 4; ++j) {
        float s = vs[j];
        s += __shfl_xor(s, 1);
        s += __shfl_xor(s, 2);
        s += __shfl_xor(s, 4);
        s += __shfl_xor(s, 8);
        rinv[j] = 1.0f / s;
    }

    // ====== pass 2: recompute s, normalize, store attn, PV (no barriers) ===
    f32x4 oacc[4];
    #pragma unroll
    for (int dt = 0; dt < 4; ++dt) oacc[dt] = vzero;
    float* attnw = attnp + (size_t)bh * ((size_t)L_ * S_) + (size_t)l0w * S_;

    #pragma unroll 1
    for (int ci = 0; ci < 64; ++ci) {
        const unsigned short* kit = kbase + ci * 2048;
        const unsigned short* vit = vbase + ci * 2048;
        uint4 f00 = *(const uint4*)(kit);
        uint4 f01 = *(const uint4*)(kit + 512);
        uint4 f10 = *(const uint4*)(kit + 1024);
        uint4 f11 = *(const uint4*)(kit + 1536);
        uint4 mp  = *(const uint4*)(mbbase + ci * 512);
        f32x4 a0 = vzero, a1 = vzero;
        a0 = __builtin_amdgcn_mfma_f32_16x16x32_bf16(
            qf[0], __builtin_bit_cast(bf16x8, f00), a0, 0, 0, 0);
        a0 = __builtin_amdgcn_mfma_f32_16x16x32_bf16(
            qf[1], __builtin_bit_cast(bf16x8, f01), a0, 0, 0, 0);
        a1 = __builtin_amdgcn_mfma_f32_16x16x32_bf16(
            qf[0], __builtin_bit_cast(bf16x8, f10), a1, 0, 0, 0);
        a1 = __builtin_amdgcn_mfma_f32_16x16x32_bf16(
            qf[1], __builtin_bit_cast(bf16x8, f11), a1, 0, 0, 0);
        float mbv[2][4];
        mbv[0][0] = h2f((unsigned short)(mp.x & 0xffff));
        mbv[0][1] = h2f((unsigned short)(mp.x >> 16));
        mbv[0][2] = h2f((unsigned short)(mp.y & 0xffff));
        mbv[0][3] = h2f((unsigned short)(mp.y >> 16));
        mbv[1][0] = h2f((unsigned short)(mp.z & 0xffff));
        mbv[1][1] = h2f((unsigned short)(mp.z >> 16));
        mbv[1][2] = h2f((unsigned short)(mp.w & 0xffff));
        mbv[1][3] = h2f((unsigned short)(mp.w >> 16));
        float a[2][4];
        #pragma unroll
        for (int j = 0; j < 4; ++j) {
            a[0][j] = __expf(fmaf(a0[j], 0.125f, mbv[0][j])) * rinv[j];
            a[1][j] = __expf(fmaf(a1[j], 0.125f, mbv[1][j])) * rinv[j];
        }
        // nontemporal attn stores; j-outer/nt-inner pairs 128B lines
        #pragma unroll
        for (int j = 0; j < 4; ++j)
          #pragma unroll
          for (int nt = 0; nt < 2; ++nt)
              __builtin_nontemporal_store(a[nt][j],
                  attnw + (size_t)(g * 4 + j) * S_ + ci * 32 + nt * 16 + li);
        // P -> per-wave LDS (wave-local transpose bounce; same-wave ds
        // ordering via lgkmcnt, no barrier)
        #pragma unroll
        for (int nt = 0; nt < 2; ++nt)
          #pragma unroll
          for (int j = 0; j < 4; ++j)
              *(unsigned short*)(pbuf + (g * 4 + j) * 80 + (nt * 16 + li) * 2)
                  = f2b(a[nt][j]);
        bf16x8 pf = *(const bf16x8*)(pbuf + li * 80 + g * 16);
        #pragma unroll
        for (int dt = 0; dt < 4; ++dt) {
            uint4 vd = *(const uint4*)(vit + dt * 512);
            oacc[dt] = __builtin_amdgcn_mfma_f32_16x16x32_bf16(
                pf, __builtin_bit_cast(bf16x8, vd), oacc[dt], 0, 0, 0);
        }
    }

    // ================= out stores (wave-local, no reduction) ===============
    float* outw = outp + ((size_t)bh * L_ + l0w) * D_;
    #pragma unroll
    for (int dt = 0; dt < 4; ++dt)
      #pragma unroll
      for (int j = 0; j < 4; ++j)
          __builtin_nontemporal_store(oacc[dt][j],
              outw + (size_t)(g * 4 + j) * D_ + dt * 16 + li);
}

extern "C" void kernel_launch(void* const* d_in, const int* in_sizes, int n_in,
                              void* d_out, int out_size, void* d_ws, size_t ws_size,
                              hipStream_t stream) {
    const float* q    = (const float*)d_in[0];
    const float* k    = (const float*)d_in[1];
    const float* v    = (const float*)d_in[2];
    const void*  mask = d_in[3];
    const float* bias = (const float*)d_in[4];

    unsigned short* k2  = (unsigned short*)d_ws;                  // 16.78 MB
    unsigned short* v2  = k2 + (size_t)8388608;                   // 16.78 MB
    unsigned short* mb2 = k2 + (size_t)16777216;                  // 33.55 MB

    float* outp  = (float*)d_out;                                 // [B,H,L,D]
    float* attnp = outp + (size_t)8388608;                        // [B,H,L,S]

    convk2_kernel<<<4096, 256, 0, stream>>>(k, k2);
    convv2_kernel<<<4096, 256, 0, stream>>>(v, v2);
    fusemb2_kernel<<<8192, 256, 0, stream>>>(bias, mask, mb2);
    attn_main_kernel<<<2048, 256, 0, stream>>>(q, mb2, k2, v2, outp, attnp);
}

// Round 11
// 410.666 us; speedup vs baseline: 1.0702x; 1.0702x over previous
//
#include <hip/hip_runtime.h>
#include <hip/hip_bf16.h>
#include <stdint.h>

#define L_ 2048
#define S_ 2048
#define D_ 64

typedef float f32x4 __attribute__((ext_vector_type(4)));
typedef __bf16 bf16x8 __attribute__((ext_vector_type(8)));

__device__ __forceinline__ unsigned short f2b(float x) {
    return __builtin_bit_cast(unsigned short, (__bf16)x);
}
__device__ __forceinline__ float h2f(unsigned short u) {
    return (float)__builtin_bit_cast(_Float16, u);
}
// force a wave-uniform pointer into SGPRs (HK readfirstlane hoist): loads
// against it use the SADDR form (s[base] + 32-bit voffset) -> frees VGPRs.
__device__ __forceinline__ const char* uni(const void* p) {
    unsigned long long u = (unsigned long long)p;
    unsigned lo = (unsigned)__builtin_amdgcn_readfirstlane((int)(unsigned)u);
    unsigned hi = (unsigned)__builtin_amdgcn_readfirstlane((int)(unsigned)(u >> 32));
    return (const char*)(((unsigned long long)hi << 32) | lo);
}
// bias/mask f16 component (nt,j) of a 16B mb2 unit, consumed inline
__device__ __forceinline__ float mbc(uint4 mp, int nt, int j) {
    unsigned v = nt ? (j < 2 ? mp.z : mp.w) : (j < 2 ? mp.x : mp.y);
    return h2f((j & 1) ? (unsigned short)(v >> 16) : (unsigned short)(v & 0xffff));
}

// ============ prep 1: K fp32 -> K2 bf16 in per-(ci,lane) frag order ========
// K2 flat 16B units: t = ((((bh*8+it)*8+w)*2+nt)*2+ks)*64 + lan
// value e of unit = K[bh][s = it*256+w*32+nt*16+li][d = ks*32+g*8+e]
// main kernel: ci = it*8+w s-chunk of 32; within chunk unit (nt*2+ks)*64+lan
__global__ void convk2_kernel(const float* __restrict__ k, unsigned short* __restrict__ k2) {
    const int t = blockIdx.x * 256 + threadIdx.x;       // 1,048,576 total
    const int lan = t & 63, ks = (t >> 6) & 1, nt = (t >> 7) & 1;
    const int w = (t >> 8) & 7, it = (t >> 11) & 7, bh = t >> 14;
    const int li = lan & 15, g = lan >> 4;
    const int s  = it * 256 + w * 32 + nt * 16 + li;
    const int d0 = ks * 32 + g * 8;
    const float* src = k + ((size_t)bh * S_ + s) * D_ + d0;
    float4 a = *(const float4*)src;
    float4 b = *(const float4*)(src + 4);
    uint4 o;
    o.x = (unsigned)f2b(a.x) | ((unsigned)f2b(a.y) << 16);
    o.y = (unsigned)f2b(a.z) | ((unsigned)f2b(a.w) << 16);
    o.z = (unsigned)f2b(b.x) | ((unsigned)f2b(b.y) << 16);
    o.w = (unsigned)f2b(b.z) | ((unsigned)f2b(b.w) << 16);
    *(uint4*)(k2 + (size_t)t * 8) = o;
}

// ============ prep 2: V fp32 -> V2 bf16 frag order =========================
// V2 16B units: t = ((((bh*8+it)*8+w)*4+dt)*64) + lan
// value e = V[bh][s = it*256+w*32+g*8+e][d = dt*16+li]
// main kernel: within ci chunk, unit dt*64+lan
__global__ void convv2_kernel(const float* __restrict__ v, unsigned short* __restrict__ v2) {
    const int t = blockIdx.x * 256 + threadIdx.x;       // 1,048,576 total
    const int lan = t & 63, dt = (t >> 6) & 3;
    const int w = (t >> 8) & 7, it = (t >> 11) & 7, bh = t >> 14;
    const int li = lan & 15, g = lan >> 4;
    const int s0 = it * 256 + w * 32 + g * 8;
    const int d  = dt * 16 + li;
    unsigned short o[8];
    #pragma unroll
    for (int e = 0; e < 8; ++e)
        o[e] = f2b(v[((size_t)bh * S_ + s0 + e) * D_ + d]);
    uint4 u;
    u.x = (unsigned)o[0] | ((unsigned)o[1] << 16);
    u.y = (unsigned)o[2] | ((unsigned)o[3] << 16);
    u.z = (unsigned)o[4] | ((unsigned)o[5] << 16);
    u.w = (unsigned)o[6] | ((unsigned)o[7] << 16);
    *(uint4*)(v2 + (size_t)t * 8) = u;
}

// ============ prep 3: bias+mask -> mb2 f16 in per-(lt16,ci,lane) order =====
// mb2 16B units: t = (((b*128+lt)*8+it)*512) + tid512; per 16-row slice lt
// contiguous in ci: slice_base + ci*512 shorts.
// val[nt*4+j] = masked ? -60000 : bias[b][lt*16+g*4+j][it*256+w*32+nt*16+li]
__global__ void fusemb2_kernel(const float* __restrict__ bias, const void* __restrict__ maskp,
                               unsigned short* __restrict__ mb2) {
    const unsigned* mw = (const unsigned*)maskp;
    int is4 = 1;
    for (int i = 0; i < 64; ++i) {
        unsigned wv = mw[i];
        if (!(wv == 0u || wv == 1u || wv == 0x3F800000u)) { is4 = 0; break; }
    }
    const int t = blockIdx.x * 256 + threadIdx.x;       // 2,097,152 total
    const int tid = t & 511, it = (t >> 9) & 7, lt = (t >> 12) & 127, b = t >> 19;
    const int w = tid >> 6, lan = tid & 63, g = lan >> 4, li = lan & 15;
    const unsigned short NEG = __builtin_bit_cast(unsigned short, (_Float16)(-60000.0f));
    const int* maski = (const int*)maskp;
    const unsigned char* maskb = (const unsigned char*)maskp;
    unsigned short o[8];
    #pragma unroll
    for (int nt = 0; nt < 2; ++nt)
      #pragma unroll
      for (int j = 0; j < 4; ++j) {
          size_t idx = ((size_t)b * L_ + lt * 16 + g * 4 + j) * S_
                     + it * 256 + w * 32 + nt * 16 + li;
          int m = is4 ? (maski[idx] != 0) : (maskb[idx] != 0);
          o[nt * 4 + j] = m ? NEG
                            : __builtin_bit_cast(unsigned short, (_Float16)bias[idx]);
      }
    uint4 u;
    u.x = (unsigned)o[0] | ((unsigned)o[1] << 16);
    u.y = (unsigned)o[2] | ((unsigned)o[3] << 16);
    u.z = (unsigned)o[4] | ((unsigned)o[5] << 16);
    u.w = (unsigned)o[6] | ((unsigned)o[7] << 16);
    *(uint4*)(mb2 + (size_t)t * 8) = u;
}

// ============ main fused attention: fat waves, 4 blocks/CU, no spills ======
// Round-8 fat-wave structure (1024 blocks x 4 autonomous waves, 32 rows/wave
// via shared-K rg pair, 2-pass defer-max, zero barriers) made to FIT the
// 128-VGPR budget of __launch_bounds__(256,4) -> all 1024 blocks resident,
// single generation (R8 ran 768+256 at 3/CU), 16 waves/CU at R8's traffic:
// (1) SGPR base pointers via readfirstlane (6 streams x 2 VGPR freed);
// (2) QK for both rg first (kf dies), then V loads (shared by both rg),
//     then per-rg epilogue -> peak live ~115;
// (3) bias/mask consumed inline (no mbv arrays).
// Ranking evidence R8(391) < R9(404,spilled) < R10(439,thin tiles): fat
// tiles beat occupancy; this adds packing+occupancy WITHOUT losing fatness.
__launch_bounds__(256, 4)
__global__ void attn_main_kernel(const float* __restrict__ q,
                                 const unsigned short* __restrict__ mb2,
                                 const unsigned short* __restrict__ k2,
                                 const unsigned short* __restrict__ v2,
                                 float* __restrict__ outp,
                                 float* __restrict__ attnp)
{
    __shared__ __align__(16) char lds[10240];    // 4 waves x 2 rg x 1280 B
    const int tid = threadIdx.x;
    const int w = tid >> 6, lan = tid & 63, g = lan >> 4, li = lan & 15;

    // bijective XCD chunking (1024 % 8 == 0): XCD x gets 128 consecutive c.
    // c = ((b*16+h)*16 + stripe): per XCD = 8 consecutive (b,h) x 16 stripes
    // -> 8 heads' K2/V2 (4.2 MB) L2-hot; mb2 streams from L3.
    const int c      = ((blockIdx.x & 7) << 7) | (blockIdx.x >> 3);
    const int b      = c >> 8;
    const int h      = (c >> 4) & 15;
    const int stripe = c & 15;
    const int bh     = (b << 4) | h;
    const int l0w    = stripe * 128 + w * 32;    // this wave's 32-row base
    const int lt0    = stripe * 8 + w * 2;       // 16-row slice index (+rg)

    // SGPR stream bases (wave-uniform)
    const char* skb  = uni(k2 + (size_t)bh * 131072);
    const char* svb  = uni(v2 + (size_t)bh * 131072);
    const char* smb0 = uni(mb2 + (size_t)(b * 128 + lt0) * 32768);
    const char* smb1 = smb0 + 65536;
    const char* sat  = uni(attnp + (size_t)bh * ((size_t)L_ * S_) + (size_t)l0w * S_);
    const char* sot  = uni(outp + ((size_t)bh * L_ + l0w) * D_);
    const int vo = lan * 16;                     // shared per-lane 16B offset
    char* pb0 = lds + (w * 2) * 1280;            // per-(wave,rg) P bounce
    char* pb1 = pb0 + 1280;
    const f32x4 vzero = {0.f, 0.f, 0.f, 0.f};

    // ---- Q fragments: rg x ks, held in regs across both passes ----
    bf16x8 qf[2][2];
    #pragma unroll
    for (int rg = 0; rg < 2; ++rg)
      #pragma unroll
      for (int ks = 0; ks < 2; ++ks) {
        const float* qp = q + ((size_t)bh * L_ + (l0w + rg * 16 + li)) * D_ + ks * 32 + g * 8;
        float4 xv = *(const float4*)qp;
        float4 yv = *(const float4*)(qp + 4);
        bf16x8 f;
        f[0]=(__bf16)xv.x; f[1]=(__bf16)xv.y; f[2]=(__bf16)xv.z; f[3]=(__bf16)xv.w;
        f[4]=(__bf16)yv.x; f[5]=(__bf16)yv.y; f[6]=(__bf16)yv.z; f[7]=(__bf16)yv.w;
        qf[rg][ks] = f;
    }

    // ================= pass 1: row sums (registers only) =================
    float vs[2][4] = {{0.f,0.f,0.f,0.f},{0.f,0.f,0.f,0.f}};
    #pragma unroll 1
    for (int ci = 0; ci < 64; ++ci) {
        const char* kc = skb + (vo + ci * 4096);
        uint4 kf0 = *(const uint4*)(kc);
        uint4 kf1 = *(const uint4*)(kc + 1024);
        uint4 kf2 = *(const uint4*)(kc + 2048);
        uint4 kf3 = *(const uint4*)(kc + 3072);
        uint4 mp0 = *(const uint4*)(smb0 + (vo + ci * 1024));
        uint4 mp1 = *(const uint4*)(smb1 + (vo + ci * 1024));
        f32x4 s00 = vzero, s01 = vzero, s10 = vzero, s11 = vzero;
        s00 = __builtin_amdgcn_mfma_f32_16x16x32_bf16(
            qf[0][0], __builtin_bit_cast(bf16x8, kf0), s00, 0, 0, 0);
        s00 = __builtin_amdgcn_mfma_f32_16x16x32_bf16(
            qf[0][1], __builtin_bit_cast(bf16x8, kf1), s00, 0, 0, 0);
        s01 = __builtin_amdgcn_mfma_f32_16x16x32_bf16(
            qf[0][0], __builtin_bit_cast(bf16x8, kf2), s01, 0, 0, 0);
        s01 = __builtin_amdgcn_mfma_f32_16x16x32_bf16(
            qf[0][1], __builtin_bit_cast(bf16x8, kf3), s01, 0, 0, 0);
        s10 = __builtin_amdgcn_mfma_f32_16x16x32_bf16(
            qf[1][0], __builtin_bit_cast(bf16x8, kf0), s10, 0, 0, 0);
        s10 = __builtin_amdgcn_mfma_f32_16x16x32_bf16(
            qf[1][1], __builtin_bit_cast(bf16x8, kf1), s10, 0, 0, 0);
        s11 = __builtin_amdgcn_mfma_f32_16x16x32_bf16(
            qf[1][0], __builtin_bit_cast(bf16x8, kf2), s11, 0, 0, 0);
        s11 = __builtin_amdgcn_mfma_f32_16x16x32_bf16(
            qf[1][1], __builtin_bit_cast(bf16x8, kf3), s11, 0, 0, 0);
        #pragma unroll
        for (int j = 0; j < 4; ++j) {
            vs[0][j] += __expf(fmaf(s00[j], 0.125f, mbc(mp0, 0, j)))
                      + __expf(fmaf(s01[j], 0.125f, mbc(mp0, 1, j)));
            vs[1][j] += __expf(fmaf(s10[j], 0.125f, mbc(mp1, 0, j)))
                      + __expf(fmaf(s11[j], 0.125f, mbc(mp1, 1, j)));
        }
    }
    // wave-local reduce over 16 li lanes -> 1/sum (no barrier, no LDS)
    float rinv[2][4];
    #pragma unroll
    for (int rg = 0; rg < 2; ++rg)
      #pragma unroll
      for (int j = 0; j < 4; ++j) {
        float s = vs[rg][j];
        s += __shfl_xor(s, 1);
        s += __shfl_xor(s, 2);
        s += __shfl_xor(s, 4);
        s += __shfl_xor(s, 8);
        rinv[rg][j] = 1.0f / s;
    }

    // ====== pass 2: recompute s, normalize, store attn, PV (no barriers) ===
    f32x4 oacc[2][4];
    #pragma unroll
    for (int rg = 0; rg < 2; ++rg)
      #pragma unroll
      for (int dt = 0; dt < 4; ++dt) oacc[rg][dt] = vzero;

    #pragma unroll 1
    for (int ci = 0; ci < 64; ++ci) {
        const char* kc = skb + (vo + ci * 4096);
        uint4 kf0 = *(const uint4*)(kc);
        uint4 kf1 = *(const uint4*)(kc + 1024);
        uint4 kf2 = *(const uint4*)(kc + 2048);
        uint4 kf3 = *(const uint4*)(kc + 3072);
        uint4 mp0 = *(const uint4*)(smb0 + (vo + ci * 1024));
        uint4 mp1 = *(const uint4*)(smb1 + (vo + ci * 1024));
        // QK^T for both rg while kf live; kf dead afterwards
        f32x4 s00 = vzero, s01 = vzero, s10 = vzero, s11 = vzero;
        s00 = __builtin_amdgcn_mfma_f32_16x16x32_bf16(
            qf[0][0], __builtin_bit_cast(bf16x8, kf0), s00, 0, 0, 0);
        s00 = __builtin_amdgcn_mfma_f32_16x16x32_bf16(
            qf[0][1], __builtin_bit_cast(bf16x8, kf1), s00, 0, 0, 0);
        s01 = __builtin_amdgcn_mfma_f32_16x16x32_bf16(
            qf[0][0], __builtin_bit_cast(bf16x8, kf2), s01, 0, 0, 0);
        s01 = __builtin_amdgcn_mfma_f32_16x16x32_bf16(
            qf[0][1], __builtin_bit_cast(bf16x8, kf3), s01, 0, 0, 0);
        s10 = __builtin_amdgcn_mfma_f32_16x16x32_bf16(
            qf[1][0], __builtin_bit_cast(bf16x8, kf0), s10, 0, 0, 0);
        s10 = __builtin_amdgcn_mfma_f32_16x16x32_bf16(
            qf[1][1], __builtin_bit_cast(bf16x8, kf1), s10, 0, 0, 0);
        s11 = __builtin_amdgcn_mfma_f32_16x16x32_bf16(
            qf[1][0], __builtin_bit_cast(bf16x8, kf2), s11, 0, 0, 0);
        s11 = __builtin_amdgcn_mfma_f32_16x16x32_bf16(
            qf[1][1], __builtin_bit_cast(bf16x8, kf3), s11, 0, 0, 0);
        // V fragments (shared by both rg)
        const char* vc = svb + (vo + ci * 4096);
        uint4 vf0 = *(const uint4*)(vc);
        uint4 vf1 = *(const uint4*)(vc + 1024);
        uint4 vf2 = *(const uint4*)(vc + 2048);
        uint4 vf3 = *(const uint4*)(vc + 3072);
        // per-rg epilogue: exp/normalize -> attn stores -> pbuf -> PV
        #pragma unroll
        for (int rg = 0; rg < 2; ++rg) {
            const uint4 mp = rg ? mp1 : mp0;
            const f32x4 sa = rg ? s10 : s00;
            const f32x4 sb = rg ? s11 : s01;
            char* pbuf = rg ? pb1 : pb0;
            float a[2][4];
            #pragma unroll
            for (int j = 0; j < 4; ++j) {
                a[0][j] = __expf(fmaf(sa[j], 0.125f, mbc(mp, 0, j))) * rinv[rg][j];
                a[1][j] = __expf(fmaf(sb[j], 0.125f, mbc(mp, 1, j))) * rinv[rg][j];
            }
            // nontemporal attn stores; j-outer/nt-inner pairs 128B lines
            #pragma unroll
            for (int j = 0; j < 4; ++j)
              #pragma unroll
              for (int nt = 0; nt < 2; ++nt)
                  __builtin_nontemporal_store(a[nt][j],
                      (float*)sat + (size_t)(rg * 16 + g * 4 + j) * S_
                                  + ci * 32 + nt * 16 + li);
            // P -> per-(wave,rg) LDS transpose bounce (same-wave lgkmcnt
            // ordering, no barrier)
            #pragma unroll
            for (int nt = 0; nt < 2; ++nt)
              #pragma unroll
              for (int j = 0; j < 4; ++j)
                  *(unsigned short*)(pbuf + (g * 4 + j) * 80 + (nt * 16 + li) * 2)
                      = f2b(a[nt][j]);
            bf16x8 pf = *(const bf16x8*)(pbuf + li * 80 + g * 16);
            oacc[rg][0] = __builtin_amdgcn_mfma_f32_16x16x32_bf16(
                pf, __builtin_bit_cast(bf16x8, vf0), oacc[rg][0], 0, 0, 0);
            oacc[rg][1] = __builtin_amdgcn_mfma_f32_16x16x32_bf16(
                pf, __builtin_bit_cast(bf16x8, vf1), oacc[rg][1], 0, 0, 0);
            oacc[rg][2] = __builtin_amdgcn_mfma_f32_16x16x32_bf16(
                pf, __builtin_bit_cast(bf16x8, vf2), oacc[rg][2], 0, 0, 0);
            oacc[rg][3] = __builtin_amdgcn_mfma_f32_16x16x32_bf16(
                pf, __builtin_bit_cast(bf16x8, vf3), oacc[rg][3], 0, 0, 0);
        }
    }

    // ================= out stores (wave-local, no reduction) ===============
    #pragma unroll
    for (int rg = 0; rg < 2; ++rg)
      #pragma unroll
      for (int dt = 0; dt < 4; ++dt)
        #pragma unroll
        for (int j = 0; j < 4; ++j)
            __builtin_nontemporal_store(oacc[rg][dt][j],
                (float*)sot + (size_t)(rg * 16 + g * 4 + j) * D_ + dt * 16 + li);
}

extern "C" void kernel_launch(void* const* d_in, const int* in_sizes, int n_in,
                              void* d_out, int out_size, void* d_ws, size_t ws_size,
                              hipStream_t stream) {
    const float* q    = (const float*)d_in[0];
    const float* k    = (const float*)d_in[1];
    const float* v    = (const float*)d_in[2];
    const void*  mask = d_in[3];
    const float* bias = (const float*)d_in[4];

    unsigned short* k2  = (unsigned short*)d_ws;                  // 16.78 MB
    unsigned short* v2  = k2 + (size_t)8388608;                   // 16.78 MB
    unsigned short* mb2 = k2 + (size_t)16777216;                  // 33.55 MB

    float* outp  = (float*)d_out;                                 // [B,H,L,D]
    float* attnp = outp + (size_t)8388608;                        // [B,H,L,S]

    convk2_kernel<<<4096, 256, 0, stream>>>(k, k2);
    convv2_kernel<<<4096, 256, 0, stream>>>(v, v2);
    fusemb2_kernel<<<8192, 256, 0, stream>>>(bias, mask, mb2);
    attn_main_kernel<<<1024, 256, 0, stream>>>(q, mb2, k2, v2, outp, attnp);
}

// Round 12
// 370.623 us; speedup vs baseline: 1.1858x; 1.1080x over previous
//
#include <hip/hip_runtime.h>
#include <hip/hip_bf16.h>
#include <stdint.h>

#define L_ 2048
#define S_ 2048
#define D_ 64

typedef float f32x4 __attribute__((ext_vector_type(4)));
typedef __bf16 bf16x8 __attribute__((ext_vector_type(8)));

__device__ __forceinline__ unsigned short f2b(float x) {
    return __builtin_bit_cast(unsigned short, (__bf16)x);
}
__device__ __forceinline__ float h2f(unsigned short u) {
    return (float)__builtin_bit_cast(_Float16, u);
}

// ============ fused prep: K->K2, V->V2, bias+mask->mb2 in ONE launch =======
// blocks [0,4096): K fp32 -> K2 bf16 per-(ci,lane) frag order
//   K2 16B units: t = ((((bh*8+it)*8+w)*2+nt)*2+ks)*64 + lan
//   value e = K[bh][s=it*256+w*32+nt*16+li][d=ks*32+g*8+e]
// blocks [4096,8192): V fp32 -> V2 bf16 frag order
//   V2 16B units: t = ((((bh*8+it)*8+w)*4+dt)*64) + lan
//   value e = V[bh][s=it*256+w*32+g*8+e][d=dt*16+li]
// blocks [8192,16384): bias+mask -> mb2 f16 per-(lt16,ci,lane) order
//   mb2 16B units: t = (((b*128+lt)*8+it)*512) + tid512
//   val[nt*4+j] = masked ? -60000 : bias[b][lt*16+g*4+j][it*256+w*32+nt*16+li]
// All three are BW-bound; fusing removes two launch/drain boundaries.
__global__ void prep_all_kernel(const float* __restrict__ k, unsigned short* __restrict__ k2,
                                const float* __restrict__ v, unsigned short* __restrict__ v2,
                                const float* __restrict__ bias, const void* __restrict__ maskp,
                                unsigned short* __restrict__ mb2) {
    const int blk = blockIdx.x;
    if (blk < 4096) {
        const int t = blk * 256 + threadIdx.x;          // 1,048,576 total
        const int lan = t & 63, ks = (t >> 6) & 1, nt = (t >> 7) & 1;
        const int w = (t >> 8) & 7, it = (t >> 11) & 7, bh = t >> 14;
        const int li = lan & 15, g = lan >> 4;
        const int s  = it * 256 + w * 32 + nt * 16 + li;
        const int d0 = ks * 32 + g * 8;
        const float* src = k + ((size_t)bh * S_ + s) * D_ + d0;
        float4 a = *(const float4*)src;
        float4 b = *(const float4*)(src + 4);
        uint4 o;
        o.x = (unsigned)f2b(a.x) | ((unsigned)f2b(a.y) << 16);
        o.y = (unsigned)f2b(a.z) | ((unsigned)f2b(a.w) << 16);
        o.z = (unsigned)f2b(b.x) | ((unsigned)f2b(b.y) << 16);
        o.w = (unsigned)f2b(b.z) | ((unsigned)f2b(b.w) << 16);
        *(uint4*)(k2 + (size_t)t * 8) = o;
    } else if (blk < 8192) {
        const int t = (blk - 4096) * 256 + threadIdx.x; // 1,048,576 total
        const int lan = t & 63, dt = (t >> 6) & 3;
        const int w = (t >> 8) & 7, it = (t >> 11) & 7, bh = t >> 14;
        const int li = lan & 15, g = lan >> 4;
        const int s0 = it * 256 + w * 32 + g * 8;
        const int d  = dt * 16 + li;
        unsigned short o[8];
        #pragma unroll
        for (int e = 0; e < 8; ++e)
            o[e] = f2b(v[((size_t)bh * S_ + s0 + e) * D_ + d]);
        uint4 u;
        u.x = (unsigned)o[0] | ((unsigned)o[1] << 16);
        u.y = (unsigned)o[2] | ((unsigned)o[3] << 16);
        u.z = (unsigned)o[4] | ((unsigned)o[5] << 16);
        u.w = (unsigned)o[6] | ((unsigned)o[7] << 16);
        *(uint4*)(v2 + (size_t)t * 8) = u;
    } else {
        const unsigned* mw = (const unsigned*)maskp;
        int is4 = 1;
        for (int i = 0; i < 64; ++i) {
            unsigned wv = mw[i];
            if (!(wv == 0u || wv == 1u || wv == 0x3F800000u)) { is4 = 0; break; }
        }
        const int t = (blk - 8192) * 256 + threadIdx.x; // 2,097,152 total
        const int tid = t & 511, it = (t >> 9) & 7, lt = (t >> 12) & 127, b = t >> 19;
        const int w = tid >> 6, lan = tid & 63, g = lan >> 4, li = lan & 15;
        const unsigned short NEG = __builtin_bit_cast(unsigned short, (_Float16)(-60000.0f));
        const int* maski = (const int*)maskp;
        const unsigned char* maskb = (const unsigned char*)maskp;
        unsigned short o[8];
        #pragma unroll
        for (int nt = 0; nt < 2; ++nt)
          #pragma unroll
          for (int j = 0; j < 4; ++j) {
              size_t idx = ((size_t)b * L_ + lt * 16 + g * 4 + j) * S_
                         + it * 256 + w * 32 + nt * 16 + li;
              int m = is4 ? (maski[idx] != 0) : (maskb[idx] != 0);
              o[nt * 4 + j] = m ? NEG
                                : __builtin_bit_cast(unsigned short, (_Float16)bias[idx]);
          }
        uint4 u;
        u.x = (unsigned)o[0] | ((unsigned)o[1] << 16);
        u.y = (unsigned)o[2] | ((unsigned)o[3] << 16);
        u.z = (unsigned)o[4] | ((unsigned)o[5] << 16);
        u.w = (unsigned)o[6] | ((unsigned)o[7] << 16);
        *(uint4*)(mb2 + (size_t)t * 8) = u;
    }
}

// ============ main fused attention: fat waves, zero barriers (R8 + mb2pf) ==
// R8 structure verbatim (1024 blocks x 4 autonomous waves, 32 rows/wave via
// shared-K rg pair, 2-pass defer-max, global->register streams, K register
// double-buffer, __launch_bounds__(256,3)) -- the best measured config (391):
// beat 4-blk/CU variants three times (R9 404 spill, R10 439 thin, R11 410).
// ONE addition: mb2 register prefetch (mp0n/mp1n, R7-proven pattern). mb2
// streams from L3 (~600-900cy) but was consumed ~250cy after its load --
// the only un-prefetched stream in the loop. +8 VGPR (~158 live) stays
// under the 170-reg budget of 3 blocks/CU -> residency unchanged.
__launch_bounds__(256, 3)
__global__ void attn_main_kernel(const float* __restrict__ q,
                                 const unsigned short* __restrict__ mb2,
                                 const unsigned short* __restrict__ k2,
                                 const unsigned short* __restrict__ v2,
                                 float* __restrict__ outp,
                                 float* __restrict__ attnp)
{
    __shared__ __align__(16) char lds[10240];    // 4 waves x 2 rg x 1280 B
    const int tid = threadIdx.x;
    const int w = tid >> 6, lan = tid & 63, g = lan >> 4, li = lan & 15;

    // bijective XCD chunking (1024 % 8 == 0): XCD x gets 128 consecutive c.
    // c = ((b*16+h)*16 + stripe): per XCD = 8 consecutive (b,h) x 16 stripes
    // -> 8 heads' K2/V2 (4.2 MB) L2-hot; mb2 streams from L3.
    const int c      = ((blockIdx.x & 7) << 7) | (blockIdx.x >> 3);
    const int b      = c >> 8;
    const int h      = (c >> 4) & 15;
    const int stripe = c & 15;
    const int bh     = (b << 4) | h;
    const int l0w    = stripe * 128 + w * 32;    // this wave's 32-row base
    const int lt0    = stripe * 8 + w * 2;       // 16-row slice index (+rg)

    const unsigned short* mbb0 = mb2 + (size_t)(b * 128 + lt0) * 32768 + (size_t)lan * 8;
    const unsigned short* mbb1 = mbb0 + 32768;
    const unsigned short* kb   = k2 + (size_t)bh * 131072 + (size_t)lan * 8;
    const unsigned short* vb   = v2 + (size_t)bh * 131072 + (size_t)lan * 8;
    char* pb0 = lds + (w * 2 + 0) * 1280;        // per-(wave,rg) P bounce
    char* pb1 = lds + (w * 2 + 1) * 1280;
    const f32x4 vzero = {0.f, 0.f, 0.f, 0.f};

    // ---- Q fragments: rg x ks, held in regs across both passes ----
    bf16x8 qf[2][2];
    #pragma unroll
    for (int rg = 0; rg < 2; ++rg)
      #pragma unroll
      for (int ks = 0; ks < 2; ++ks) {
        const float* qp = q + ((size_t)bh * L_ + (l0w + rg * 16 + li)) * D_ + ks * 32 + g * 8;
        float4 xv = *(const float4*)qp;
        float4 yv = *(const float4*)(qp + 4);
        bf16x8 f;
        f[0]=(__bf16)xv.x; f[1]=(__bf16)xv.y; f[2]=(__bf16)xv.z; f[3]=(__bf16)xv.w;
        f[4]=(__bf16)yv.x; f[5]=(__bf16)yv.y; f[6]=(__bf16)yv.z; f[7]=(__bf16)yv.w;
        qf[rg][ks] = f;
    }

    // ================= pass 1: row sums (registers only) =================
    float vs[2][4] = {{0.f,0.f,0.f,0.f},{0.f,0.f,0.f,0.f}};
    uint4 kf[4], kn[4];
    #pragma unroll
    for (int ff = 0; ff < 4; ++ff) kf[ff] = *(const uint4*)(kb + ff * 512);
    uint4 mp0 = *(const uint4*)(mbb0);
    uint4 mp1 = *(const uint4*)(mbb1);
    #pragma unroll 1
    for (int ci = 0; ci < 64; ++ci) {
        const int cn = (ci < 63) ? ci + 1 : 63;  // harmless re-load on last
        #pragma unroll
        for (int ff = 0; ff < 4; ++ff)
            kn[ff] = *(const uint4*)(kb + cn * 2048 + ff * 512);
        uint4 mp0n = *(const uint4*)(mbb0 + cn * 512);
        uint4 mp1n = *(const uint4*)(mbb1 + cn * 512);
        #pragma unroll
        for (int rg = 0; rg < 2; ++rg) {
            const uint4 mp = rg ? mp1 : mp0;
            f32x4 a0 = vzero, a1 = vzero;
            a0 = __builtin_amdgcn_mfma_f32_16x16x32_bf16(
                qf[rg][0], __builtin_bit_cast(bf16x8, kf[0]), a0, 0, 0, 0);
            a0 = __builtin_amdgcn_mfma_f32_16x16x32_bf16(
                qf[rg][1], __builtin_bit_cast(bf16x8, kf[1]), a0, 0, 0, 0);
            a1 = __builtin_amdgcn_mfma_f32_16x16x32_bf16(
                qf[rg][0], __builtin_bit_cast(bf16x8, kf[2]), a1, 0, 0, 0);
            a1 = __builtin_amdgcn_mfma_f32_16x16x32_bf16(
                qf[rg][1], __builtin_bit_cast(bf16x8, kf[3]), a1, 0, 0, 0);
            float mbv[2][4];
            mbv[0][0] = h2f((unsigned short)(mp.x & 0xffff));
            mbv[0][1] = h2f((unsigned short)(mp.x >> 16));
            mbv[0][2] = h2f((unsigned short)(mp.y & 0xffff));
            mbv[0][3] = h2f((unsigned short)(mp.y >> 16));
            mbv[1][0] = h2f((unsigned short)(mp.z & 0xffff));
            mbv[1][1] = h2f((unsigned short)(mp.z >> 16));
            mbv[1][2] = h2f((unsigned short)(mp.w & 0xffff));
            mbv[1][3] = h2f((unsigned short)(mp.w >> 16));
            #pragma unroll
            for (int j = 0; j < 4; ++j) {
                float e0 = __expf(fmaf(a0[j], 0.125f, mbv[0][j]));
                float e1 = __expf(fmaf(a1[j], 0.125f, mbv[1][j]));
                vs[rg][j] += e0 + e1;
            }
        }
        #pragma unroll
        for (int ff = 0; ff < 4; ++ff) kf[ff] = kn[ff];
        mp0 = mp0n; mp1 = mp1n;
    }
    // wave-local reduce over 16 li lanes -> 1/sum (no barrier, no LDS)
    float rinv[2][4];
    #pragma unroll
    for (int rg = 0; rg < 2; ++rg)
      #pragma unroll
      for (int j = 0; j < 4; ++j) {
        float s = vs[rg][j];
        s += __shfl_xor(s, 1);
        s += __shfl_xor(s, 2);
        s += __shfl_xor(s, 4);
        s += __shfl_xor(s, 8);
        rinv[rg][j] = 1.0f / s;
    }

    // ====== pass 2: recompute s, normalize, store attn, PV (no barriers) ===
    f32x4 oacc[2][4];
    #pragma unroll
    for (int rg = 0; rg < 2; ++rg)
      #pragma unroll
      for (int dt = 0; dt < 4; ++dt) oacc[rg][dt] = vzero;
    float* attnw = attnp + (size_t)bh * ((size_t)L_ * S_) + (size_t)l0w * S_;

    #pragma unroll
    for (int ff = 0; ff < 4; ++ff) kf[ff] = *(const uint4*)(kb + ff * 512);
    mp0 = *(const uint4*)(mbb0);
    mp1 = *(const uint4*)(mbb1);
    #pragma unroll 1
    for (int ci = 0; ci < 64; ++ci) {
        const int cn = (ci < 63) ? ci + 1 : 63;
        #pragma unroll
        for (int ff = 0; ff < 4; ++ff)
            kn[ff] = *(const uint4*)(kb + cn * 2048 + ff * 512);
        uint4 mp0n = *(const uint4*)(mbb0 + cn * 512);
        uint4 mp1n = *(const uint4*)(mbb1 + cn * 512);
        uint4 vf[4];
        #pragma unroll
        for (int dt = 0; dt < 4; ++dt)
            vf[dt] = *(const uint4*)(vb + ci * 2048 + dt * 512);
        #pragma unroll
        for (int rg = 0; rg < 2; ++rg) {
            const uint4 mp = rg ? mp1 : mp0;
            char* pbuf = rg ? pb1 : pb0;
            f32x4 a0 = vzero, a1 = vzero;
            a0 = __builtin_amdgcn_mfma_f32_16x16x32_bf16(
                qf[rg][0], __builtin_bit_cast(bf16x8, kf[0]), a0, 0, 0, 0);
            a0 = __builtin_amdgcn_mfma_f32_16x16x32_bf16(
                qf[rg][1], __builtin_bit_cast(bf16x8, kf[1]), a0, 0, 0, 0);
            a1 = __builtin_amdgcn_mfma_f32_16x16x32_bf16(
                qf[rg][0], __builtin_bit_cast(bf16x8, kf[2]), a1, 0, 0, 0);
            a1 = __builtin_amdgcn_mfma_f32_16x16x32_bf16(
                qf[rg][1], __builtin_bit_cast(bf16x8, kf[3]), a1, 0, 0, 0);
            float mbv[2][4];
            mbv[0][0] = h2f((unsigned short)(mp.x & 0xffff));
            mbv[0][1] = h2f((unsigned short)(mp.x >> 16));
            mbv[0][2] = h2f((unsigned short)(mp.y & 0xffff));
            mbv[0][3] = h2f((unsigned short)(mp.y >> 16));
            mbv[1][0] = h2f((unsigned short)(mp.z & 0xffff));
            mbv[1][1] = h2f((unsigned short)(mp.z >> 16));
            mbv[1][2] = h2f((unsigned short)(mp.w & 0xffff));
            mbv[1][3] = h2f((unsigned short)(mp.w >> 16));
            float a[2][4];
            #pragma unroll
            for (int j = 0; j < 4; ++j) {
                a[0][j] = __expf(fmaf(a0[j], 0.125f, mbv[0][j])) * rinv[rg][j];
                a[1][j] = __expf(fmaf(a1[j], 0.125f, mbv[1][j])) * rinv[rg][j];
            }
            // nontemporal attn stores; j-outer/nt-inner pairs 128B lines
            float* aw = attnw + (size_t)(rg * 16) * S_;
            #pragma unroll
            for (int j = 0; j < 4; ++j)
              #pragma unroll
              for (int nt = 0; nt < 2; ++nt)
                  __builtin_nontemporal_store(a[nt][j],
                      aw + (size_t)(g * 4 + j) * S_ + ci * 32 + nt * 16 + li);
            // P -> per-(wave,rg) LDS transpose bounce (same-wave lgkmcnt
            // ordering, no barrier)
            #pragma unroll
            for (int nt = 0; nt < 2; ++nt)
              #pragma unroll
              for (int j = 0; j < 4; ++j)
                  *(unsigned short*)(pbuf + (g * 4 + j) * 80 + (nt * 16 + li) * 2)
                      = f2b(a[nt][j]);
            bf16x8 pf = *(const bf16x8*)(pbuf + li * 80 + g * 16);
            #pragma unroll
            for (int dt = 0; dt < 4; ++dt)
                oacc[rg][dt] = __builtin_amdgcn_mfma_f32_16x16x32_bf16(
                    pf, __builtin_bit_cast(bf16x8, vf[dt]), oacc[rg][dt], 0, 0, 0);
        }
        #pragma unroll
        for (int ff = 0; ff < 4; ++ff) kf[ff] = kn[ff];
        mp0 = mp0n; mp1 = mp1n;
    }

    // ================= out stores (wave-local, no reduction) ===============
    #pragma unroll
    for (int rg = 0; rg < 2; ++rg) {
        float* outw = outp + ((size_t)bh * L_ + (l0w + rg * 16)) * D_;
        #pragma unroll
        for (int dt = 0; dt < 4; ++dt)
          #pragma unroll
          for (int j = 0; j < 4; ++j)
              __builtin_nontemporal_store(oacc[rg][dt][j],
                  outw + (size_t)(g * 4 + j) * D_ + dt * 16 + li);
    }
}

extern "C" void kernel_launch(void* const* d_in, const int* in_sizes, int n_in,
                              void* d_out, int out_size, void* d_ws, size_t ws_size,
                              hipStream_t stream) {
    const float* q    = (const float*)d_in[0];
    const float* k    = (const float*)d_in[1];
    const float* v    = (const float*)d_in[2];
    const void*  mask = d_in[3];
    const float* bias = (const float*)d_in[4];

    unsigned short* k2  = (unsigned short*)d_ws;                  // 16.78 MB
    unsigned short* v2  = k2 + (size_t)8388608;                   // 16.78 MB
    unsigned short* mb2 = k2 + (size_t)16777216;                  // 33.55 MB

    float* outp  = (float*)d_out;                                 // [B,H,L,D]
    float* attnp = outp + (size_t)8388608;                        // [B,H,L,S]

    prep_all_kernel<<<16384, 256, 0, stream>>>(k, k2, v, v2, bias, mask, mb2);
    attn_main_kernel<<<1024, 256, 0, stream>>>(q, mb2, k2, v2, outp, attnp);
}

// Round 13
// 354.227 us; speedup vs baseline: 1.2407x; 1.0463x over previous
//
#include <hip/hip_runtime.h>
#include <hip/hip_bf16.h>
#include <stdint.h>

#define L_ 2048
#define S_ 2048
#define D_ 64

typedef float f32x4 __attribute__((ext_vector_type(4)));
typedef __bf16 bf16x8 __attribute__((ext_vector_type(8)));

__device__ __forceinline__ unsigned short f2b(float x) {
    return __builtin_bit_cast(unsigned short, (__bf16)x);
}
__device__ __forceinline__ float h2f(unsigned short u) {
    return (float)__builtin_bit_cast(_Float16, u);
}

// ============ fused prep: K->K2, V->V2, bias+mask->mb2 in ONE launch =======
// blocks [0,4096): K fp32 -> K2 bf16 per-(ci,lane) frag order
//   K2 16B units: t = ((((bh*8+it)*8+w)*2+nt)*2+ks)*64 + lan
//   value e = K[bh][s=it*256+w*32+nt*16+li][d=ks*32+g*8+e]
// blocks [4096,8192): V fp32 -> V2 bf16 frag order
//   V2 16B units: t = ((((bh*8+it)*8+w)*4+dt)*64) + lan
//   value e = V[bh][s=it*256+w*32+g*8+e][d=dt*16+li]
// blocks [8192,16384): bias+mask -> mb2 f16 per-(lt16,ci,lane) order
//   mb2 16B units: t = (((b*128+lt)*8+it)*512) + tid512
//   val[nt*4+j] = masked ? -60000 : bias[b][lt*16+g*4+j][it*256+w*32+nt*16+li]
// All three are BW-bound; fusing removes two launch/drain boundaries.
__global__ void prep_all_kernel(const float* __restrict__ k, unsigned short* __restrict__ k2,
                                const float* __restrict__ v, unsigned short* __restrict__ v2,
                                const float* __restrict__ bias, const void* __restrict__ maskp,
                                unsigned short* __restrict__ mb2) {
    const int blk = blockIdx.x;
    if (blk < 4096) {
        const int t = blk * 256 + threadIdx.x;          // 1,048,576 total
        const int lan = t & 63, ks = (t >> 6) & 1, nt = (t >> 7) & 1;
        const int w = (t >> 8) & 7, it = (t >> 11) & 7, bh = t >> 14;
        const int li = lan & 15, g = lan >> 4;
        const int s  = it * 256 + w * 32 + nt * 16 + li;
        const int d0 = ks * 32 + g * 8;
        const float* src = k + ((size_t)bh * S_ + s) * D_ + d0;
        float4 a = *(const float4*)src;
        float4 b = *(const float4*)(src + 4);
        uint4 o;
        o.x = (unsigned)f2b(a.x) | ((unsigned)f2b(a.y) << 16);
        o.y = (unsigned)f2b(a.z) | ((unsigned)f2b(a.w) << 16);
        o.z = (unsigned)f2b(b.x) | ((unsigned)f2b(b.y) << 16);
        o.w = (unsigned)f2b(b.z) | ((unsigned)f2b(b.w) << 16);
        *(uint4*)(k2 + (size_t)t * 8) = o;
    } else if (blk < 8192) {
        const int t = (blk - 4096) * 256 + threadIdx.x; // 1,048,576 total
        const int lan = t & 63, dt = (t >> 6) & 3;
        const int w = (t >> 8) & 7, it = (t >> 11) & 7, bh = t >> 14;
        const int li = lan & 15, g = lan >> 4;
        const int s0 = it * 256 + w * 32 + g * 8;
        const int d  = dt * 16 + li;
        unsigned short o[8];
        #pragma unroll
        for (int e = 0; e < 8; ++e)
            o[e] = f2b(v[((size_t)bh * S_ + s0 + e) * D_ + d]);
        uint4 u;
        u.x = (unsigned)o[0] | ((unsigned)o[1] << 16);
        u.y = (unsigned)o[2] | ((unsigned)o[3] << 16);
        u.z = (unsigned)o[4] | ((unsigned)o[5] << 16);
        u.w = (unsigned)o[6] | ((unsigned)o[7] << 16);
        *(uint4*)(v2 + (size_t)t * 8) = u;
    } else {
        const unsigned* mw = (const unsigned*)maskp;
        int is4 = 1;
        for (int i = 0; i < 64; ++i) {
            unsigned wv = mw[i];
            if (!(wv == 0u || wv == 1u || wv == 0x3F800000u)) { is4 = 0; break; }
        }
        const int t = (blk - 8192) * 256 + threadIdx.x; // 2,097,152 total
        const int tid = t & 511, it = (t >> 9) & 7, lt = (t >> 12) & 127, b = t >> 19;
        const int w = tid >> 6, lan = tid & 63, g = lan >> 4, li = lan & 15;
        const unsigned short NEG = __builtin_bit_cast(unsigned short, (_Float16)(-60000.0f));
        const int* maski = (const int*)maskp;
        const unsigned char* maskb = (const unsigned char*)maskp;
        unsigned short o[8];
        #pragma unroll
        for (int nt = 0; nt < 2; ++nt)
          #pragma unroll
          for (int j = 0; j < 4; ++j) {
              size_t idx = ((size_t)b * L_ + lt * 16 + g * 4 + j) * S_
                         + it * 256 + w * 32 + nt * 16 + li;
              int m = is4 ? (maski[idx] != 0) : (maskb[idx] != 0);
              o[nt * 4 + j] = m ? NEG
                                : __builtin_bit_cast(unsigned short, (_Float16)bias[idx]);
          }
        uint4 u;
        u.x = (unsigned)o[0] | ((unsigned)o[1] << 16);
        u.y = (unsigned)o[2] | ((unsigned)o[3] << 16);
        u.z = (unsigned)o[4] | ((unsigned)o[5] << 16);
        u.w = (unsigned)o[6] | ((unsigned)o[7] << 16);
        *(uint4*)(mb2 + (size_t)t * 8) = u;
    }
}

// ============ main fused attention: fat waves, zero barriers (R12+setprio) =
// R12 structure verbatim (1024 blocks x 4 autonomous waves, 32 rows/wave via
// shared-K rg pair, 2-pass defer-max, K+mb2 register double-buffer,
// __launch_bounds__(256,3)) -- best measured config (370.6). ONE addition:
// s_setprio(1)/(0) around each 4-MFMA cluster (T5). Our waves are exactly
// the m191 attn regime (independent waves at different phases, no barriers)
// where setprio measured +4-7%: priority keeps the matrix pipe fed while
// sibling waves issue their store/exp phases. No traffic/register/numerics
// change (absmax must remain 0.015625).
__launch_bounds__(256, 3)
__global__ void attn_main_kernel(const float* __restrict__ q,
                                 const unsigned short* __restrict__ mb2,
                                 const unsigned short* __restrict__ k2,
                                 const unsigned short* __restrict__ v2,
                                 float* __restrict__ outp,
                                 float* __restrict__ attnp)
{
    __shared__ __align__(16) char lds[10240];    // 4 waves x 2 rg x 1280 B
    const int tid = threadIdx.x;
    const int w = tid >> 6, lan = tid & 63, g = lan >> 4, li = lan & 15;

    // bijective XCD chunking (1024 % 8 == 0): XCD x gets 128 consecutive c.
    // c = ((b*16+h)*16 + stripe): per XCD = 8 consecutive (b,h) x 16 stripes
    // -> 8 heads' K2/V2 (4.2 MB) L2-hot; mb2 streams from L3.
    const int c      = ((blockIdx.x & 7) << 7) | (blockIdx.x >> 3);
    const int b      = c >> 8;
    const int h      = (c >> 4) & 15;
    const int stripe = c & 15;
    const int bh     = (b << 4) | h;
    const int l0w    = stripe * 128 + w * 32;    // this wave's 32-row base
    const int lt0    = stripe * 8 + w * 2;       // 16-row slice index (+rg)

    const unsigned short* mbb0 = mb2 + (size_t)(b * 128 + lt0) * 32768 + (size_t)lan * 8;
    const unsigned short* mbb1 = mbb0 + 32768;
    const unsigned short* kb   = k2 + (size_t)bh * 131072 + (size_t)lan * 8;
    const unsigned short* vb   = v2 + (size_t)bh * 131072 + (size_t)lan * 8;
    char* pb0 = lds + (w * 2 + 0) * 1280;        // per-(wave,rg) P bounce
    char* pb1 = lds + (w * 2 + 1) * 1280;
    const f32x4 vzero = {0.f, 0.f, 0.f, 0.f};

    // ---- Q fragments: rg x ks, held in regs across both passes ----
    bf16x8 qf[2][2];
    #pragma unroll
    for (int rg = 0; rg < 2; ++rg)
      #pragma unroll
      for (int ks = 0; ks < 2; ++ks) {
        const float* qp = q + ((size_t)bh * L_ + (l0w + rg * 16 + li)) * D_ + ks * 32 + g * 8;
        float4 xv = *(const float4*)qp;
        float4 yv = *(const float4*)(qp + 4);
        bf16x8 f;
        f[0]=(__bf16)xv.x; f[1]=(__bf16)xv.y; f[2]=(__bf16)xv.z; f[3]=(__bf16)xv.w;
        f[4]=(__bf16)yv.x; f[5]=(__bf16)yv.y; f[6]=(__bf16)yv.z; f[7]=(__bf16)yv.w;
        qf[rg][ks] = f;
    }

    // ================= pass 1: row sums (registers only) =================
    float vs[2][4] = {{0.f,0.f,0.f,0.f},{0.f,0.f,0.f,0.f}};
    uint4 kf[4], kn[4];
    #pragma unroll
    for (int ff = 0; ff < 4; ++ff) kf[ff] = *(const uint4*)(kb + ff * 512);
    uint4 mp0 = *(const uint4*)(mbb0);
    uint4 mp1 = *(const uint4*)(mbb1);
    #pragma unroll 1
    for (int ci = 0; ci < 64; ++ci) {
        const int cn = (ci < 63) ? ci + 1 : 63;  // harmless re-load on last
        #pragma unroll
        for (int ff = 0; ff < 4; ++ff)
            kn[ff] = *(const uint4*)(kb + cn * 2048 + ff * 512);
        uint4 mp0n = *(const uint4*)(mbb0 + cn * 512);
        uint4 mp1n = *(const uint4*)(mbb1 + cn * 512);
        #pragma unroll
        for (int rg = 0; rg < 2; ++rg) {
            const uint4 mp = rg ? mp1 : mp0;
            f32x4 a0 = vzero, a1 = vzero;
            __builtin_amdgcn_s_setprio(1);
            a0 = __builtin_amdgcn_mfma_f32_16x16x32_bf16(
                qf[rg][0], __builtin_bit_cast(bf16x8, kf[0]), a0, 0, 0, 0);
            a0 = __builtin_amdgcn_mfma_f32_16x16x32_bf16(
                qf[rg][1], __builtin_bit_cast(bf16x8, kf[1]), a0, 0, 0, 0);
            a1 = __builtin_amdgcn_mfma_f32_16x16x32_bf16(
                qf[rg][0], __builtin_bit_cast(bf16x8, kf[2]), a1, 0, 0, 0);
            a1 = __builtin_amdgcn_mfma_f32_16x16x32_bf16(
                qf[rg][1], __builtin_bit_cast(bf16x8, kf[3]), a1, 0, 0, 0);
            __builtin_amdgcn_s_setprio(0);
            float mbv[2][4];
            mbv[0][0] = h2f((unsigned short)(mp.x & 0xffff));
            mbv[0][1] = h2f((unsigned short)(mp.x >> 16));
            mbv[0][2] = h2f((unsigned short)(mp.y & 0xffff));
            mbv[0][3] = h2f((unsigned short)(mp.y >> 16));
            mbv[1][0] = h2f((unsigned short)(mp.z & 0xffff));
            mbv[1][1] = h2f((unsigned short)(mp.z >> 16));
            mbv[1][2] = h2f((unsigned short)(mp.w & 0xffff));
            mbv[1][3] = h2f((unsigned short)(mp.w >> 16));
            #pragma unroll
            for (int j = 0; j < 4; ++j) {
                float e0 = __expf(fmaf(a0[j], 0.125f, mbv[0][j]));
                float e1 = __expf(fmaf(a1[j], 0.125f, mbv[1][j]));
                vs[rg][j] += e0 + e1;
            }
        }
        #pragma unroll
        for (int ff = 0; ff < 4; ++ff) kf[ff] = kn[ff];
        mp0 = mp0n; mp1 = mp1n;
    }
    // wave-local reduce over 16 li lanes -> 1/sum (no barrier, no LDS)
    float rinv[2][4];
    #pragma unroll
    for (int rg = 0; rg < 2; ++rg)
      #pragma unroll
      for (int j = 0; j < 4; ++j) {
        float s = vs[rg][j];
        s += __shfl_xor(s, 1);
        s += __shfl_xor(s, 2);
        s += __shfl_xor(s, 4);
        s += __shfl_xor(s, 8);
        rinv[rg][j] = 1.0f / s;
    }

    // ====== pass 2: recompute s, normalize, store attn, PV (no barriers) ===
    f32x4 oacc[2][4];
    #pragma unroll
    for (int rg = 0; rg < 2; ++rg)
      #pragma unroll
      for (int dt = 0; dt < 4; ++dt) oacc[rg][dt] = vzero;
    float* attnw = attnp + (size_t)bh * ((size_t)L_ * S_) + (size_t)l0w * S_;

    #pragma unroll
    for (int ff = 0; ff < 4; ++ff) kf[ff] = *(const uint4*)(kb + ff * 512);
    mp0 = *(const uint4*)(mbb0);
    mp1 = *(const uint4*)(mbb1);
    #pragma unroll 1
    for (int ci = 0; ci < 64; ++ci) {
        const int cn = (ci < 63) ? ci + 1 : 63;
        #pragma unroll
        for (int ff = 0; ff < 4; ++ff)
            kn[ff] = *(const uint4*)(kb + cn * 2048 + ff * 512);
        uint4 mp0n = *(const uint4*)(mbb0 + cn * 512);
        uint4 mp1n = *(const uint4*)(mbb1 + cn * 512);
        uint4 vf[4];
        #pragma unroll
        for (int dt = 0; dt < 4; ++dt)
            vf[dt] = *(const uint4*)(vb + ci * 2048 + dt * 512);
        #pragma unroll
        for (int rg = 0; rg < 2; ++rg) {
            const uint4 mp = rg ? mp1 : mp0;
            char* pbuf = rg ? pb1 : pb0;
            f32x4 a0 = vzero, a1 = vzero;
            __builtin_amdgcn_s_setprio(1);
            a0 = __builtin_amdgcn_mfma_f32_16x16x32_bf16(
                qf[rg][0], __builtin_bit_cast(bf16x8, kf[0]), a0, 0, 0, 0);
            a0 = __builtin_amdgcn_mfma_f32_16x16x32_bf16(
                qf[rg][1], __builtin_bit_cast(bf16x8, kf[1]), a0, 0, 0, 0);
            a1 = __builtin_amdgcn_mfma_f32_16x16x32_bf16(
                qf[rg][0], __builtin_bit_cast(bf16x8, kf[2]), a1, 0, 0, 0);
            a1 = __builtin_amdgcn_mfma_f32_16x16x32_bf16(
                qf[rg][1], __builtin_bit_cast(bf16x8, kf[3]), a1, 0, 0, 0);
            __builtin_amdgcn_s_setprio(0);
            float mbv[2][4];
            mbv[0][0] = h2f((unsigned short)(mp.x & 0xffff));
            mbv[0][1] = h2f((unsigned short)(mp.x >> 16));
            mbv[0][2] = h2f((unsigned short)(mp.y & 0xffff));
            mbv[0][3] = h2f((unsigned short)(mp.y >> 16));
            mbv[1][0] = h2f((unsigned short)(mp.z & 0xffff));
            mbv[1][1] = h2f((unsigned short)(mp.z >> 16));
            mbv[1][2] = h2f((unsigned short)(mp.w & 0xffff));
            mbv[1][3] = h2f((unsigned short)(mp.w >> 16));
            float a[2][4];
            #pragma unroll
            for (int j = 0; j < 4; ++j) {
                a[0][j] = __expf(fmaf(a0[j], 0.125f, mbv[0][j])) * rinv[rg][j];
                a[1][j] = __expf(fmaf(a1[j], 0.125f, mbv[1][j])) * rinv[rg][j];
            }
            // nontemporal attn stores; j-outer/nt-inner pairs 128B lines
            float* aw = attnw + (size_t)(rg * 16) * S_;
            #pragma unroll
            for (int j = 0; j < 4; ++j)
              #pragma unroll
              for (int nt = 0; nt < 2; ++nt)
                  __builtin_nontemporal_store(a[nt][j],
                      aw + (size_t)(g * 4 + j) * S_ + ci * 32 + nt * 16 + li);
            // P -> per-(wave,rg) LDS transpose bounce (same-wave lgkmcnt
            // ordering, no barrier)
            #pragma unroll
            for (int nt = 0; nt < 2; ++nt)
              #pragma unroll
              for (int j = 0; j < 4; ++j)
                  *(unsigned short*)(pbuf + (g * 4 + j) * 80 + (nt * 16 + li) * 2)
                      = f2b(a[nt][j]);
            bf16x8 pf = *(const bf16x8*)(pbuf + li * 80 + g * 16);
            __builtin_amdgcn_s_setprio(1);
            #pragma unroll
            for (int dt = 0; dt < 4; ++dt)
                oacc[rg][dt] = __builtin_amdgcn_mfma_f32_16x16x32_bf16(
                    pf, __builtin_bit_cast(bf16x8, vf[dt]), oacc[rg][dt], 0, 0, 0);
            __builtin_amdgcn_s_setprio(0);
        }
        #pragma unroll
        for (int ff = 0; ff < 4; ++ff) kf[ff] = kn[ff];
        mp0 = mp0n; mp1 = mp1n;
    }

    // ================= out stores (wave-local, no reduction) ===============
    #pragma unroll
    for (int rg = 0; rg < 2; ++rg) {
        float* outw = outp + ((size_t)bh * L_ + (l0w + rg * 16)) * D_;
        #pragma unroll
        for (int dt = 0; dt < 4; ++dt)
          #pragma unroll
          for (int j = 0; j < 4; ++j)
              __builtin_nontemporal_store(oacc[rg][dt][j],
                  outw + (size_t)(g * 4 + j) * D_ + dt * 16 + li);
    }
}

extern "C" void kernel_launch(void* const* d_in, const int* in_sizes, int n_in,
                              void* d_out, int out_size, void* d_ws, size_t ws_size,
                              hipStream_t stream) {
    const float* q    = (const float*)d_in[0];
    const float* k    = (const float*)d_in[1];
    const float* v    = (const float*)d_in[2];
    const void*  mask = d_in[3];
    const float* bias = (const float*)d_in[4];

    unsigned short* k2  = (unsigned short*)d_ws;                  // 16.78 MB
    unsigned short* v2  = k2 + (size_t)8388608;                   // 16.78 MB
    unsigned short* mb2 = k2 + (size_t)16777216;                  // 33.55 MB

    float* outp  = (float*)d_out;                                 // [B,H,L,D]
    float* attnp = outp + (size_t)8388608;                        // [B,H,L,S]

    prep_all_kernel<<<16384, 256, 0, stream>>>(k, k2, v, v2, bias, mask, mb2);
    attn_main_kernel<<<1024, 256, 0, stream>>>(q, mb2, k2, v2, outp, attnp);
}